// Round 8
// baseline (249.407 us; speedup 1.0000x reference)
//
#include <hip/hip_runtime.h>
#include <hip/hip_bf16.h>

typedef __bf16 bf16;
typedef bf16 bf16x8 __attribute__((ext_vector_type(8)));
typedef bf16 bf16x4 __attribute__((ext_vector_type(4)));
typedef float f32x4 __attribute__((ext_vector_type(4)));
typedef float f32x16 __attribute__((ext_vector_type(16)));
typedef unsigned int u32;
typedef u32 u32x4 __attribute__((ext_vector_type(4)));

static constexpr int SEQ    = 4096;
static constexpr int DMODEL = 1024;
static constexpr int NHEADS = 16;
static constexpr int DHEAD  = 64;
static constexpr int QKV3   = 3 * DMODEL;  // 3072
static constexpr float SMAX = 64.0f;       // Cauchy-Schwarz bound on q.k after rmsnorm
static constexpr float LOG2E = 1.44269504088896341f;
// R4 lesson: softmax stays exp2(fma(st, LOG2E, -SMAX*LOG2E)) with unscaled q.

// Async global->LDS 16B copy. LDS dest must be wave-uniform base + lane*16.
__device__ inline void gld16(const bf16* g, bf16* l) {
    __builtin_amdgcn_global_load_lds(
        (const __attribute__((address_space(1))) void*)g,
        (__attribute__((address_space(3))) void*)l, 16, 0, 0);
}

__device__ inline bf16x8 load8(const float* src) {
    float4 a = *(const float4*)(src);
    float4 b = *(const float4*)(src + 4);
    bf16x8 r;
    r[0] = (bf16)a.x; r[1] = (bf16)a.y; r[2] = (bf16)a.z; r[3] = (bf16)a.w;
    r[4] = (bf16)b.x; r[5] = (bf16)b.y; r[6] = (bf16)b.z; r[7] = (bf16)b.w;
    return r;
}

__device__ inline f32x16 zero16() {
    f32x16 r;
#pragma unroll
    for (int i = 0; i < 16; ++i) r[i] = 0.f;
    return r;
}

// ---------------------------------------------------------------------------
static constexpr size_t NX = (size_t)SEQ * DMODEL;     // 4194304
static constexpr size_t NW = (size_t)QKV3 * DMODEL;    // 3145728
static constexpr size_t NO = (size_t)DMODEL * DMODEL;  // 1048576

__global__ __launch_bounds__(256)
void cvt_all(const float* __restrict__ x, const float* __restrict__ Wqkv,
             const float* __restrict__ Wo, bf16* __restrict__ outbase) {
    const size_t e = ((size_t)blockIdx.x * 256 + threadIdx.x) * 8;
    const float* src;
    if (e < NX)            src = x + e;
    else if (e < NX + NW)  src = Wqkv + (e - NX);
    else                   src = Wo + (e - NX - NW);
    *(bf16x8*)(outbase + e) = load8(src);
}

// ---------------------------------------------------------------------------
// QKV GEMM with fused per-head RMSNorm (q,k) and fused V-transpose epilogue.
// (unchanged)
// ---------------------------------------------------------------------------
__global__ __launch_bounds__(256)
void gemm_qkv(const bf16* __restrict__ A, const bf16* __restrict__ W,
              const float* __restrict__ bias, const float* __restrict__ wq,
              const float* __restrict__ wk, bf16* __restrict__ qkv,
              bf16* __restrict__ Vt) {
    __shared__ __align__(16) bf16 As[128 * 32];
    __shared__ __align__(16) bf16 Ws[128 * 32];
    const int tid  = threadIdx.x;
    const int wave = tid >> 6;
    const int ll   = tid & 15;
    const int quad = (tid & 63) >> 4;
    const int wm   = (wave >> 1) * 64;
    const int wn   = (wave & 1) * 64;
    const int m0 = blockIdx.y * 128;
    const int n0 = blockIdx.x * 128;

    f32x4 acc[4][4];
#pragma unroll
    for (int i = 0; i < 4; ++i)
#pragma unroll
        for (int j = 0; j < 4; ++j) acc[i][j] = (f32x4){0.f, 0.f, 0.f, 0.f};

    for (int k0 = 0; k0 < DMODEL; k0 += 32) {
        __syncthreads();
#pragma unroll
        for (int i = 0; i < 2; ++i) {
            const int idx = i * 256 + tid;
            const int row = idx >> 2;
            const int c   = (idx & 3) ^ ((row >> 1) & 3);
            gld16(&A[(size_t)(m0 + row) * DMODEL + k0 + c * 8], As + idx * 8);
            gld16(&W[(size_t)(n0 + row) * DMODEL + k0 + c * 8], Ws + idx * 8);
        }
        __syncthreads();
        bf16x8 af[4], bfr[4];
#pragma unroll
        for (int mi = 0; mi < 4; ++mi) {
            const int row = wm + mi * 16 + ll;
            af[mi] = *(const bf16x8*)(As + (row * 4 + (quad ^ ((ll >> 1) & 3))) * 8);
        }
#pragma unroll
        for (int ni = 0; ni < 4; ++ni) {
            const int row = wn + ni * 16 + ll;
            bfr[ni] = *(const bf16x8*)(Ws + (row * 4 + (quad ^ ((ll >> 1) & 3))) * 8);
        }
#pragma unroll
        for (int mi = 0; mi < 4; ++mi)
#pragma unroll
            for (int ni = 0; ni < 4; ++ni)
                acc[mi][ni] = __builtin_amdgcn_mfma_f32_16x16x32_bf16(
                    af[mi], bfr[ni], acc[mi][ni], 0, 0, 0);
    }

    float bvn[4];
#pragma unroll
    for (int ni = 0; ni < 4; ++ni) bvn[ni] = bias[n0 + wn + ni * 16 + ll];

    const int sect = (n0 + wn) >> 10;      // 0=q, 1=k, 2=v (wave-uniform)
    if (sect < 2) {
        const float* wv = sect ? wk : wq;
        float wvl[4];
#pragma unroll
        for (int ni = 0; ni < 4; ++ni) wvl[ni] = wv[ni * 16 + ll];
#pragma unroll
        for (int mi = 0; mi < 4; ++mi)
#pragma unroll
            for (int r = 0; r < 4; ++r) {
                float xf[4];
                float ss = 0.f;
#pragma unroll
                for (int ni = 0; ni < 4; ++ni) {
                    xf[ni] = (float)(bf16)(acc[mi][ni][r] + bvn[ni]);
                    ss += xf[ni] * xf[ni];
                }
#pragma unroll
                for (int off = 1; off < 16; off <<= 1) ss += __shfl_xor(ss, off);
                const float scale = rsqrtf(ss * (1.0f / 64.0f) + 1e-6f);
                const int row = m0 + wm + mi * 16 + quad * 4 + r;
#pragma unroll
                for (int ni = 0; ni < 4; ++ni)
                    qkv[(size_t)row * QKV3 + n0 + wn + ni * 16 + ll] =
                        (bf16)(xf[ni] * scale * wvl[ni]);
            }
    } else {
        const int h = (n0 + wn - 2 * DMODEL) >> 6;   // head (wave-uniform)
#pragma unroll
        for (int mi = 0; mi < 4; ++mi) {
            const int kv = m0 + wm + mi * 16 + quad * 4;
#pragma unroll
            for (int ni = 0; ni < 4; ++ni) {
                bf16x4 vv;
#pragma unroll
                for (int r = 0; r < 4; ++r) vv[r] = (bf16)(acc[mi][ni][r] + bvn[ni]);
                *(bf16x4*)(Vt + (size_t)(h * DHEAD + ni * 16 + ll) * SEQ + kv) = vv;
            }
        }
    }
}

// ---------------------------------------------------------------------------
// Output GEMM (unchanged).
// ---------------------------------------------------------------------------
__global__ __launch_bounds__(256)
void gemm_out(const bf16* __restrict__ A, const bf16* __restrict__ W,
              const float* __restrict__ bias, float* __restrict__ C) {
    __shared__ __align__(16) bf16 As[128 * 32];
    __shared__ __align__(16) bf16 Ws[64 * 32];
    const int tid  = threadIdx.x;
    const int wave = tid >> 6;
    const int ll   = tid & 15;
    const int quad = (tid & 63) >> 4;
    const int m0 = blockIdx.y * 128;
    const int n0 = blockIdx.x * 64;

    f32x4 acc[2][4];
#pragma unroll
    for (int i = 0; i < 2; ++i)
#pragma unroll
        for (int j = 0; j < 4; ++j) acc[i][j] = (f32x4){0.f, 0.f, 0.f, 0.f};

    for (int k0 = 0; k0 < DMODEL; k0 += 32) {
        __syncthreads();
#pragma unroll
        for (int i = 0; i < 2; ++i) {
            const int idx = i * 256 + tid;
            const int row = idx >> 2;
            const int c   = (idx & 3) ^ ((row >> 1) & 3);
            gld16(&A[(size_t)(m0 + row) * DMODEL + k0 + c * 8], As + idx * 8);
        }
        {
            const int j   = tid;                 // 0..255
            const int row = j >> 2;              // 0..63
            const int c   = (j & 3) ^ ((row >> 1) & 3);
            gld16(&W[(size_t)(n0 + row) * DMODEL + k0 + c * 8], Ws + j * 8);
        }
        __syncthreads();
        bf16x8 af[2], bfr[4];
#pragma unroll
        for (int mi = 0; mi < 2; ++mi) {
            const int row = wave * 32 + mi * 16 + ll;
            af[mi] = *(const bf16x8*)(As + (row * 4 + (quad ^ ((ll >> 1) & 3))) * 8);
        }
#pragma unroll
        for (int ni = 0; ni < 4; ++ni) {
            const int row = ni * 16 + ll;
            bfr[ni] = *(const bf16x8*)(Ws + (row * 4 + (quad ^ ((ll >> 1) & 3))) * 8);
        }
#pragma unroll
        for (int mi = 0; mi < 2; ++mi)
#pragma unroll
            for (int ni = 0; ni < 4; ++ni)
                acc[mi][ni] = __builtin_amdgcn_mfma_f32_16x16x32_bf16(
                    af[mi], bfr[ni], acc[mi][ni], 0, 0, 0);
    }
#pragma unroll
    for (int ni = 0; ni < 4; ++ni) {
        const int col = n0 + ni * 16 + ll;
        const float bv = bias[col];
#pragma unroll
        for (int mi = 0; mi < 2; ++mi)
#pragma unroll
            for (int r = 0; r < 4; ++r) {
                const int row = m0 + wave * 32 + mi * 16 + quad * 4 + r;
                C[(size_t)row * DMODEL + col] = acc[mi][ni][r] + bv;
            }
    }
}

// ---------------------------------------------------------------------------
// Flash attention R8: barrier-free wave-private kv-split.
//   Block = 64 q-rows shared by 4 waves; each wave owns one kv quarter
//   (1024 rows, 32-kv tiles) staged into its PRIVATE 16 KB LDS slice via
//   reg-staging (issue global->reg at iter top, vmcnt+ds_write at bottom).
//   NO in-loop barriers: 8 free-running waves/CU drift into different
//   phases so MFMA/VALU/LDS overlap across waves (m114 regime).
//   Epilogue: one barrier, cross-wave o/l combine in LDS, direct z write
//   (combine_halves kernel + opf traffic deleted).
//   XCD chunk swizzle: each XCD gets a contiguous 128-block chunk = 2 heads
//   so per-XCD K/V working set (2 MB) stays L2-resident.
// ---------------------------------------------------------------------------
__global__ __launch_bounds__(256, 2)
void attn_fwd(const bf16* __restrict__ qkv, const bf16* __restrict__ Vt,
              bf16* __restrict__ z) {
    __shared__ __align__(16) bf16 QS[64 * 64];        // 8 KB (Q; l4 in epilogue)
    __shared__ __align__(16) bf16 KVW[4][2][4096];    // 4 waves x 2 buf x (K 4KB|V 4KB)
    float* Os4 = (float*)&KVW[0][0][0];               // epilogue: [4][2*2*32*32] = 64 KB
    float* l4  = (float*)&QS[0];                      // epilogue: [4][2][32] = 1 KB

    const int tid  = threadIdx.x;
    const int wave = tid >> 6;
    const int lane = tid & 63;
    const int l31  = lane & 31;
    const int hh   = lane >> 5;
    const int l7   = lane & 7;

    // XCD chunk swizzle: blocks 0..1023, 8 XCDs, 128-chunks (bijective).
    const int nid  = (blockIdx.x & 7) * 128 + (blockIdx.x >> 3);
    const int head = nid >> 6;
    const int q0   = (nid & 63) * 64;

    const bf16* kbase  = qkv + DMODEL + head * DHEAD;
    const bf16* vtbase = Vt + (size_t)head * DHEAD * SEQ;
    const int kvw0 = wave * (SEQ / 4);   // this wave's kv quarter
    constexpr int NT = (SEQ / 4) / 32;   // 32 tiles of 32 kv

    // ---- prologue: stage 64 Q rows (shared), one barrier ----
#pragma unroll
    for (int i = 0; i < 2; ++i) {
        const int idx = i * 256 + tid;
        const int row = idx >> 3;
        const int c   = (idx & 7) ^ (row & 7);
        gld16(qkv + (size_t)(q0 + row) * QKV3 + head * DHEAD + c * 8, QS + idx * 8);
    }
    __syncthreads();
    bf16x8 qf[4][2];
#pragma unroll
    for (int kd = 0; kd < 4; ++kd)
#pragma unroll
        for (int qs = 0; qs < 2; ++qs) {
            const int row = qs * 32 + l31;
            qf[kd][qs] = *(const bf16x8*)(QS + (row * 8 + ((kd * 2 + hh) ^ l7)) * 8);
        }
    // QS is read-only until the epilogue barrier; no more block syncs needed.

    bf16* const myKV = &KVW[wave][0][0];   // [buf 2][K 2048 bf16 | V 2048 bf16]

    u32x4 kr[4], vr[4];
    auto issue_loads = [&](int kv0) {
#pragma unroll
        for (int j = 0; j < 4; ++j) {
            const int idx = j * 64 + lane;
            {
                const int row = idx >> 3, c = (idx & 7) ^ (row & 7);
                kr[j] = *(const u32x4*)(kbase + (size_t)(kv0 + row) * QKV3 + c * 8);
            }
            {
                const int row = idx >> 2, c = (idx & 3) ^ (row & 3);
                vr[j] = *(const u32x4*)(vtbase + (size_t)row * SEQ + kv0 + c * 8);
            }
        }
    };
    auto write_tile = [&](int buf) {
        bf16* Kd = myKV + buf * 4096;
#pragma unroll
        for (int j = 0; j < 4; ++j) {
            const int idx = j * 64 + lane;
            *(u32x4*)(Kd + idx * 8)        = kr[j];
            *(u32x4*)(Kd + 2048 + idx * 8) = vr[j];
        }
    };

    issue_loads(kvw0);
    write_tile(0);

    f32x16 o[2][2];    // [dt][qs]
    o[0][0] = zero16(); o[0][1] = zero16();
    o[1][0] = zero16(); o[1][1] = zero16();
    float lpa[2][4] = {{0.f, 0.f, 0.f, 0.f}, {0.f, 0.f, 0.f, 0.f}};

#pragma unroll 1
    for (int t = 0; t < NT; ++t) {
        if (t + 1 < NT) issue_loads(kvw0 + (t + 1) * 32);   // in flight during compute
        const bf16* Kd = myKV + (t & 1) * 4096;
        const bf16* Vd = Kd + 2048;

        // QK^T: 32 kv x 64 q (2 subtiles)
        f32x16 st0 = zero16(), st1 = zero16();
        __builtin_amdgcn_s_setprio(1);
#pragma unroll
        for (int kd = 0; kd < 4; ++kd) {
            bf16x8 kf = *(const bf16x8*)(Kd + (l31 * 8 + ((kd * 2 + hh) ^ l7)) * 8);
            st0 = __builtin_amdgcn_mfma_f32_32x32x16_bf16(kf, qf[kd][0], st0, 0, 0, 0);
            st1 = __builtin_amdgcn_mfma_f32_32x32x16_bf16(kf, qf[kd][1], st1, 0, 0, 0);
        }
        __builtin_amdgcn_s_setprio(0);

        float pf0[16], pf1[16];
#pragma unroll
        for (int r = 0; r < 16; ++r)
            pf0[r] = __builtin_amdgcn_exp2f(__builtin_fmaf(st0[r], LOG2E, -SMAX * LOG2E));
#pragma unroll
        for (int r = 0; r < 16; ++r)
            pf1[r] = __builtin_amdgcn_exp2f(__builtin_fmaf(st1[r], LOG2E, -SMAX * LOG2E));
#pragma unroll
        for (int r = 0; r < 16; ++r) lpa[0][r & 3] += pf0[r];
#pragma unroll
        for (int r = 0; r < 16; ++r) lpa[1][r & 3] += pf1[r];

#pragma unroll
        for (int cc = 0; cc < 2; ++cc) {
            u32 a1, b1, a2, b2, a3, b3, a4, b4;
            asm("v_cvt_pk_bf16_f32 %0, %1, %2" : "=v"(a1) : "v"(pf0[8 * cc + 0]), "v"(pf0[8 * cc + 1]));
            asm("v_cvt_pk_bf16_f32 %0, %1, %2" : "=v"(b1) : "v"(pf0[8 * cc + 4]), "v"(pf0[8 * cc + 5]));
            asm("v_cvt_pk_bf16_f32 %0, %1, %2" : "=v"(a2) : "v"(pf0[8 * cc + 2]), "v"(pf0[8 * cc + 3]));
            asm("v_cvt_pk_bf16_f32 %0, %1, %2" : "=v"(b2) : "v"(pf0[8 * cc + 6]), "v"(pf0[8 * cc + 7]));
            asm("v_permlane32_swap_b32 %0, %1" : "+v"(a1), "+v"(b1));
            asm("v_permlane32_swap_b32 %0, %1" : "+v"(a2), "+v"(b2));
            asm("v_cvt_pk_bf16_f32 %0, %1, %2" : "=v"(a3) : "v"(pf1[8 * cc + 0]), "v"(pf1[8 * cc + 1]));
            asm("v_cvt_pk_bf16_f32 %0, %1, %2" : "=v"(b3) : "v"(pf1[8 * cc + 4]), "v"(pf1[8 * cc + 5]));
            asm("v_cvt_pk_bf16_f32 %0, %1, %2" : "=v"(a4) : "v"(pf1[8 * cc + 2]), "v"(pf1[8 * cc + 3]));
            asm("v_cvt_pk_bf16_f32 %0, %1, %2" : "=v"(b4) : "v"(pf1[8 * cc + 6]), "v"(pf1[8 * cc + 7]));
            asm("v_permlane32_swap_b32 %0, %1" : "+v"(a3), "+v"(b3));
            asm("v_permlane32_swap_b32 %0, %1" : "+v"(a4), "+v"(b4));
            u32x4 w0, w1;
            w0[0] = a1; w0[1] = a2; w0[2] = b1; w0[3] = b2;
            w1[0] = a3; w1[1] = a4; w1[2] = b3; w1[3] = b4;
            const bf16x8 bp0 = *(const bf16x8*)&w0;
            const bf16x8 bp1 = *(const bf16x8*)&w1;
            __builtin_amdgcn_s_setprio(1);
#pragma unroll
            for (int dt = 0; dt < 2; ++dt) {
                bf16x8 vf = *(const bf16x8*)(
                    Vd + ((dt * 32 + l31) * 4 + ((cc * 2 + hh) ^ (l31 & 3))) * 8);
                o[dt][0] = __builtin_amdgcn_mfma_f32_32x32x16_bf16(vf, bp0, o[dt][0], 0, 0, 0);
                o[dt][1] = __builtin_amdgcn_mfma_f32_32x32x16_bf16(vf, bp1, o[dt][1], 0, 0, 0);
            }
            __builtin_amdgcn_s_setprio(0);
        }

        if (t + 1 < NT) write_tile((t + 1) & 1);   // waits own vmcnt only
    }

    // ---- epilogue: cross-wave combine (one barrier) ----
    float lp[2];
#pragma unroll
    for (int qs = 0; qs < 2; ++qs) {
        lp[qs] = (lpa[qs][0] + lpa[qs][1]) + (lpa[qs][2] + lpa[qs][3]);
        lp[qs] += __shfl_xor(lp[qs], 32);
    }
#pragma unroll
    for (int dt = 0; dt < 2; ++dt)
#pragma unroll
        for (int qs = 0; qs < 2; ++qs)
#pragma unroll
            for (int r = 0; r < 16; ++r) {
                const int dl = (r & 3) + 8 * (r >> 2) + 4 * hh;   // 0..31
                Os4[wave * 4096 + ((dt * 2 + qs) * 32 + dl) * 32 + l31] = o[dt][qs][r];
            }
    if (lane < 32) {
        l4[(wave * 2 + 0) * 32 + l31] = lp[0];
        l4[(wave * 2 + 1) * 32 + l31] = lp[1];
    }
    __syncthreads();

    const int q    = tid >> 2;          // 0..63
    const int dblk = (tid & 3) * 16;    // 0,16,32,48
    const int qs   = q >> 5, lq = q & 31;
    const float ltot = (l4[(0 * 2 + qs) * 32 + lq] + l4[(1 * 2 + qs) * 32 + lq]) +
                       (l4[(2 * 2 + qs) * 32 + lq] + l4[(3 * 2 + qs) * 32 + lq]);
    const float invl = 1.0f / ltot;
    bf16 obuf[16];
#pragma unroll
    for (int k = 0; k < 16; ++k) {
        const int d = dblk + k, dt = d >> 5, dl = d & 31;
        const int off = ((dt * 2 + qs) * 32 + dl) * 32 + lq;
        const float s = (Os4[off] + Os4[4096 + off]) + (Os4[8192 + off] + Os4[12288 + off]);
        obuf[k] = (bf16)(s * invl);
    }
    bf16* zp = z + (size_t)(q0 + q) * DMODEL + head * DHEAD + dblk;
    *(bf16x8*)(zp)     = *(bf16x8*)&obuf[0];
    *(bf16x8*)(zp + 8) = *(bf16x8*)&obuf[8];
}

// ---------------------------------------------------------------------------
extern "C" void kernel_launch(void* const* d_in, const int* in_sizes, int n_in,
                              void* d_out, int out_size, void* d_ws, size_t ws_size,
                              hipStream_t stream) {
    const float* x    = (const float*)d_in[0];
    const float* Wqkv = (const float*)d_in[1];
    const float* bqkv = (const float*)d_in[2];
    const float* Wo   = (const float*)d_in[3];
    const float* bo   = (const float*)d_in[4];
    const float* wq   = (const float*)d_in[5];
    const float* wk   = (const float*)d_in[6];
    float* out = (float*)d_out;

    bf16* qkv  = (bf16*)d_ws;                       // [4096][3072]  25.2 MB (v third unused)
    bf16* z    = qkv + (size_t)SEQ * QKV3;          // [4096][1024]   8.4 MB
    bf16* Vt   = z + (size_t)SEQ * DMODEL;          // [16][64][4096] 8.4 MB
    bf16* xb   = Vt + (size_t)NHEADS * DHEAD * SEQ; // [4096][1024]   8.4 MB
    bf16* Wqb  = xb + NX;                           // [3072][1024]   6.3 MB
    bf16* Wob  = Wqb + NW;                          // [1024][1024]   2.1 MB

    cvt_all<<<dim3((NX + NW + NO) / 2048), 256, 0, stream>>>(x, Wqkv, Wo, xb);

    gemm_qkv<<<dim3(QKV3 / 128, SEQ / 128), 256, 0, stream>>>(
        xb, Wqb, bqkv, wq, wk, qkv, Vt);

    attn_fwd<<<dim3(NHEADS * (SEQ / 64)), 256, 0, stream>>>(qkv, Vt, z);

    gemm_out<<<dim3(DMODEL / 64, SEQ / 128), 256, 0, stream>>>(z, Wob, bo, out);
}

// Round 9
// 228.177 us; speedup vs baseline: 1.0930x; 1.0930x over previous
//
#include <hip/hip_runtime.h>
#include <hip/hip_bf16.h>

typedef __bf16 bf16;
typedef bf16 bf16x8 __attribute__((ext_vector_type(8)));
typedef bf16 bf16x4 __attribute__((ext_vector_type(4)));
typedef float f32x4 __attribute__((ext_vector_type(4)));
typedef float f32x16 __attribute__((ext_vector_type(16)));
typedef unsigned int u32;
typedef u32 u32x4 __attribute__((ext_vector_type(4)));

static constexpr int SEQ    = 4096;
static constexpr int DMODEL = 1024;
static constexpr int NHEADS = 16;
static constexpr int DHEAD  = 64;
static constexpr int QKV3   = 3 * DMODEL;  // 3072
static constexpr float SMAX = 64.0f;       // Cauchy-Schwarz bound on q.k after rmsnorm
static constexpr float LOG2E = 1.44269504088896341f;
// R4 lesson: softmax stays exp2(fma(st, LOG2E, -SMAX*LOG2E)) with unscaled q.

// Async global->LDS 16B copy. LDS dest must be wave-uniform base + lane*16.
__device__ inline void gld16(const bf16* g, bf16* l) {
    __builtin_amdgcn_global_load_lds(
        (const __attribute__((address_space(1))) void*)g,
        (__attribute__((address_space(3))) void*)l, 16, 0, 0);
}

__device__ inline bf16x8 load8(const float* src) {
    float4 a = *(const float4*)(src);
    float4 b = *(const float4*)(src + 4);
    bf16x8 r;
    r[0] = (bf16)a.x; r[1] = (bf16)a.y; r[2] = (bf16)a.z; r[3] = (bf16)a.w;
    r[4] = (bf16)b.x; r[5] = (bf16)b.y; r[6] = (bf16)b.z; r[7] = (bf16)b.w;
    return r;
}

__device__ inline f32x16 zero16() {
    f32x16 r;
#pragma unroll
    for (int i = 0; i < 16; ++i) r[i] = 0.f;
    return r;
}

// ---------------------------------------------------------------------------
static constexpr size_t NX = (size_t)SEQ * DMODEL;     // 4194304
static constexpr size_t NW = (size_t)QKV3 * DMODEL;    // 3145728
static constexpr size_t NO = (size_t)DMODEL * DMODEL;  // 1048576

__global__ __launch_bounds__(256)
void cvt_all(const float* __restrict__ x, const float* __restrict__ Wqkv,
             const float* __restrict__ Wo, bf16* __restrict__ outbase) {
    const size_t e = ((size_t)blockIdx.x * 256 + threadIdx.x) * 8;
    const float* src;
    if (e < NX)            src = x + e;
    else if (e < NX + NW)  src = Wqkv + (e - NX);
    else                   src = Wo + (e - NX - NW);
    *(bf16x8*)(outbase + e) = load8(src);
}

// ---------------------------------------------------------------------------
// QKV GEMM with fused per-head RMSNorm (q,k) and fused V-transpose epilogue.
// R9: BK 32->64 (halves the vmcnt(0)+barrier drains per block, the m97-
// documented ~20% stall). kk ascending inside k0 -> accumulation order and
// results bit-identical to BK=32. LDS 32 KB (still >=3 blocks/CU at grid 3).
// ---------------------------------------------------------------------------
__global__ __launch_bounds__(256)
void gemm_qkv(const bf16* __restrict__ A, const bf16* __restrict__ W,
              const float* __restrict__ bias, const float* __restrict__ wq,
              const float* __restrict__ wk, bf16* __restrict__ qkv,
              bf16* __restrict__ Vt) {
    __shared__ __align__(16) bf16 As[128 * 64];   // 16 KB
    __shared__ __align__(16) bf16 Ws[128 * 64];   // 16 KB
    const int tid  = threadIdx.x;
    const int wave = tid >> 6;
    const int ll   = tid & 15;
    const int quad = (tid & 63) >> 4;
    const int wm   = (wave >> 1) * 64;
    const int wn   = (wave & 1) * 64;
    const int m0 = blockIdx.y * 128;
    const int n0 = blockIdx.x * 128;

    f32x4 acc[4][4];
#pragma unroll
    for (int i = 0; i < 4; ++i)
#pragma unroll
        for (int j = 0; j < 4; ++j) acc[i][j] = (f32x4){0.f, 0.f, 0.f, 0.f};

    for (int k0 = 0; k0 < DMODEL; k0 += 64) {
        __syncthreads();
#pragma unroll
        for (int i = 0; i < 4; ++i) {
            const int idx = i * 256 + tid;          // 0..1023
            const int row = idx >> 3;               // 0..127
            const int c   = (idx & 7) ^ (row & 7);  // 8-chunk XOR swizzle
            gld16(&A[(size_t)(m0 + row) * DMODEL + k0 + c * 8], As + idx * 8);
            gld16(&W[(size_t)(n0 + row) * DMODEL + k0 + c * 8], Ws + idx * 8);
        }
        __syncthreads();
#pragma unroll
        for (int kk = 0; kk < 2; ++kk) {
            bf16x8 af[4], bfr[4];
#pragma unroll
            for (int mi = 0; mi < 4; ++mi) {
                const int row = wm + mi * 16 + ll;
                const int p   = (kk * 4 + quad) ^ (ll & 7);
                af[mi] = *(const bf16x8*)(As + (row * 8 + p) * 8);
            }
#pragma unroll
            for (int ni = 0; ni < 4; ++ni) {
                const int row = wn + ni * 16 + ll;
                const int p   = (kk * 4 + quad) ^ (ll & 7);
                bfr[ni] = *(const bf16x8*)(Ws + (row * 8 + p) * 8);
            }
#pragma unroll
            for (int mi = 0; mi < 4; ++mi)
#pragma unroll
                for (int ni = 0; ni < 4; ++ni)
                    acc[mi][ni] = __builtin_amdgcn_mfma_f32_16x16x32_bf16(
                        af[mi], bfr[ni], acc[mi][ni], 0, 0, 0);
        }
    }

    float bvn[4];
#pragma unroll
    for (int ni = 0; ni < 4; ++ni) bvn[ni] = bias[n0 + wn + ni * 16 + ll];

    const int sect = (n0 + wn) >> 10;      // 0=q, 1=k, 2=v (wave-uniform)
    if (sect < 2) {
        const float* wv = sect ? wk : wq;
        float wvl[4];
#pragma unroll
        for (int ni = 0; ni < 4; ++ni) wvl[ni] = wv[ni * 16 + ll];
#pragma unroll
        for (int mi = 0; mi < 4; ++mi)
#pragma unroll
            for (int r = 0; r < 4; ++r) {
                float xf[4];
                float ss = 0.f;
#pragma unroll
                for (int ni = 0; ni < 4; ++ni) {
                    xf[ni] = (float)(bf16)(acc[mi][ni][r] + bvn[ni]);
                    ss += xf[ni] * xf[ni];
                }
#pragma unroll
                for (int off = 1; off < 16; off <<= 1) ss += __shfl_xor(ss, off);
                const float scale = rsqrtf(ss * (1.0f / 64.0f) + 1e-6f);
                const int row = m0 + wm + mi * 16 + quad * 4 + r;
#pragma unroll
                for (int ni = 0; ni < 4; ++ni)
                    qkv[(size_t)row * QKV3 + n0 + wn + ni * 16 + ll] =
                        (bf16)(xf[ni] * scale * wvl[ni]);
            }
    } else {
        const int h = (n0 + wn - 2 * DMODEL) >> 6;   // head (wave-uniform)
#pragma unroll
        for (int mi = 0; mi < 4; ++mi) {
            const int kv = m0 + wm + mi * 16 + quad * 4;
#pragma unroll
            for (int ni = 0; ni < 4; ++ni) {
                bf16x4 vv;
#pragma unroll
                for (int r = 0; r < 4; ++r) vv[r] = (bf16)(acc[mi][ni][r] + bvn[ni]);
                *(bf16x4*)(Vt + (size_t)(h * DHEAD + ni * 16 + ll) * SEQ + kv) = vv;
            }
        }
    }
}

// ---------------------------------------------------------------------------
// Output GEMM. R9: BK 32->64 (same drain-halving rationale; bit-identical).
// LDS 24 KB.
// ---------------------------------------------------------------------------
__global__ __launch_bounds__(256)
void gemm_out(const bf16* __restrict__ A, const bf16* __restrict__ W,
              const float* __restrict__ bias, float* __restrict__ C) {
    __shared__ __align__(16) bf16 As[128 * 64];   // 16 KB
    __shared__ __align__(16) bf16 Ws[64 * 64];    //  8 KB
    const int tid  = threadIdx.x;
    const int wave = tid >> 6;
    const int ll   = tid & 15;
    const int quad = (tid & 63) >> 4;
    const int m0 = blockIdx.y * 128;
    const int n0 = blockIdx.x * 64;

    f32x4 acc[2][4];
#pragma unroll
    for (int i = 0; i < 2; ++i)
#pragma unroll
        for (int j = 0; j < 4; ++j) acc[i][j] = (f32x4){0.f, 0.f, 0.f, 0.f};

    for (int k0 = 0; k0 < DMODEL; k0 += 64) {
        __syncthreads();
#pragma unroll
        for (int i = 0; i < 4; ++i) {
            const int idx = i * 256 + tid;          // 0..1023
            const int row = idx >> 3;               // 0..127
            const int c   = (idx & 7) ^ (row & 7);
            gld16(&A[(size_t)(m0 + row) * DMODEL + k0 + c * 8], As + idx * 8);
        }
#pragma unroll
        for (int i = 0; i < 2; ++i) {
            const int idx = i * 256 + tid;          // 0..511
            const int row = idx >> 3;               // 0..63
            const int c   = (idx & 7) ^ (row & 7);
            gld16(&W[(size_t)(n0 + row) * DMODEL + k0 + c * 8], Ws + idx * 8);
        }
        __syncthreads();
#pragma unroll
        for (int kk = 0; kk < 2; ++kk) {
            bf16x8 af[2], bfr[4];
#pragma unroll
            for (int mi = 0; mi < 2; ++mi) {
                const int row = wave * 32 + mi * 16 + ll;
                const int p   = (kk * 4 + quad) ^ (ll & 7);
                af[mi] = *(const bf16x8*)(As + (row * 8 + p) * 8);
            }
#pragma unroll
            for (int ni = 0; ni < 4; ++ni) {
                const int row = ni * 16 + ll;
                const int p   = (kk * 4 + quad) ^ (ll & 7);
                bfr[ni] = *(const bf16x8*)(Ws + (row * 8 + p) * 8);
            }
#pragma unroll
            for (int mi = 0; mi < 2; ++mi)
#pragma unroll
                for (int ni = 0; ni < 4; ++ni)
                    acc[mi][ni] = __builtin_amdgcn_mfma_f32_16x16x32_bf16(
                        af[mi], bfr[ni], acc[mi][ni], 0, 0, 0);
        }
    }
#pragma unroll
    for (int ni = 0; ni < 4; ++ni) {
        const int col = n0 + ni * 16 + ll;
        const float bv = bias[col];
#pragma unroll
        for (int mi = 0; mi < 2; ++mi)
#pragma unroll
            for (int r = 0; r < 4; ++r) {
                const int row = m0 + wave * 32 + mi * 16 + quad * 4 + r;
                C[(size_t)row * DMODEL + col] = acc[mi][ni][r] + bv;
            }
    }
}

// ---------------------------------------------------------------------------
// Flash attention: R6-exact structure (session-best). 32x32 swapped-operand,
// dbuf KV prefetch, 64 q-rows/wave, NSPLIT-way kv split (2 preferred).
// ---------------------------------------------------------------------------
template<int NSPLIT>
__global__ __launch_bounds__(256, 2)
void attn_fwd(const bf16* __restrict__ qkv, const bf16* __restrict__ Vt,
              bf16* __restrict__ z, float* __restrict__ opf,
              float* __restrict__ lsum) {
    constexpr bool PARTIAL = (NSPLIT > 1);
    __shared__ __align__(16) bf16 KV[2][2][64 * 64];   // 32768 B total
    float (*Os)[32][36] = (float(*)[32][36])(&KV[0][0][0]);  // epilogue scratch (18432 B)
    bf16* Qs = &KV[0][0][0];   // prologue Q staging: 256x64 bf16 = 32 KB (whole region)

    const int tid  = threadIdx.x;
    const int wave = tid >> 6;
    const int lane = tid & 63;
    const int l31  = lane & 31;
    const int hh   = lane >> 5;
    const int l7   = lane & 7;
    const int head = blockIdx.x;
    const int q0   = blockIdx.y * 256;
    const int half = PARTIAL ? blockIdx.z : 0;
    const int kvlen = SEQ / NSPLIT;
    const int kvbeg = half * kvlen;
    const int nt    = kvlen / 64;

    const bf16* kbase  = qkv + DMODEL + head * DHEAD;
    const bf16* vtbase = Vt + (size_t)head * DHEAD * SEQ;

    auto stage_kv = [&](int buf, int kv0) {
#pragma unroll
        for (int i = 0; i < 2; ++i) {
            const int idx = i * 256 + tid;
            const int row = idx >> 3;
            const int c   = (idx & 7) ^ (row & 7);
            gld16(kbase + (size_t)(kv0 + row) * QKV3 + c * 8, &KV[buf][0][0] + idx * 8);
            gld16(vtbase + (size_t)row * SEQ + kv0 + c * 8, &KV[buf][1][0] + idx * 8);
        }
    };

    // ---- prologue: stage 256 Q rows into the whole KV region ----
#pragma unroll
    for (int i = 0; i < 8; ++i) {
        const int idx = i * 256 + tid;
        const int row = idx >> 3;
        const int c   = (idx & 7) ^ (row & 7);
        gld16(qkv + (size_t)(q0 + row) * QKV3 + head * DHEAD + c * 8, Qs + idx * 8);
    }
    __syncthreads();
    // Q as B-fragment: n = q = lane&31 (per subtile), k = d = kd*16 + hh*8 + j
    bf16x8 qf[4][2];
#pragma unroll
    for (int kd = 0; kd < 4; ++kd)
#pragma unroll
        for (int qs = 0; qs < 2; ++qs) {
            const int row = wave * 64 + qs * 32 + l31;
            qf[kd][qs] = *(const bf16x8*)(Qs + (row * 8 + ((kd * 2 + hh) ^ l7)) * 8);
        }
    __syncthreads();   // qf reads done before KV staging overwrites region
    stage_kv(0, kvbeg);
    __syncthreads();   // buf0 ready

    f32x16 o[2][2];    // [dt][qs]
    o[0][0] = zero16(); o[0][1] = zero16();
    o[1][0] = zero16(); o[1][1] = zero16();
    float lpa[2][4] = {{0.f, 0.f, 0.f, 0.f}, {0.f, 0.f, 0.f, 0.f}};

    int cur = 0;
    for (int t = 0; t < nt; ++t) {
        if (t + 1 < nt) stage_kv(cur ^ 1, kvbeg + (t + 1) * 64);
        const bf16* Ks  = &KV[cur][0][0];
        const bf16* VTs = &KV[cur][1][0];

#pragma unroll
        for (int kvt = 0; kvt < 2; ++kvt) {
            // S^T tiles for both q-subtiles: each kf read feeds 2 MFMAs.
            f32x16 st0 = zero16(), st1 = zero16();
            __builtin_amdgcn_s_setprio(1);
#pragma unroll
            for (int kd = 0; kd < 4; ++kd) {
                bf16x8 kf = *(const bf16x8*)(
                    Ks + ((kvt * 32 + l31) * 8 + ((kd * 2 + hh) ^ l7)) * 8);
                st0 = __builtin_amdgcn_mfma_f32_32x32x16_bf16(kf, qf[kd][0], st0, 0, 0, 0);
                st1 = __builtin_amdgcn_mfma_f32_32x32x16_bf16(kf, qf[kd][1], st1, 0, 0, 0);
            }
            __builtin_amdgcn_s_setprio(0);

            float pf0[16], pf1[16];
#pragma unroll
            for (int r = 0; r < 16; ++r)
                pf0[r] = __builtin_amdgcn_exp2f(
                    __builtin_fmaf(st0[r], LOG2E, -SMAX * LOG2E));
#pragma unroll
            for (int r = 0; r < 16; ++r)
                pf1[r] = __builtin_amdgcn_exp2f(
                    __builtin_fmaf(st1[r], LOG2E, -SMAX * LOG2E));
#pragma unroll
            for (int r = 0; r < 16; ++r) lpa[0][r & 3] += pf0[r];
#pragma unroll
            for (int r = 0; r < 16; ++r) lpa[1][r & 3] += pf1[r];

            // P^T -> bf16 B-fragments; each vf read feeds 2 MFMAs.
#pragma unroll
            for (int cc = 0; cc < 2; ++cc) {
                u32 a1, b1, a2, b2, a3, b3, a4, b4;
                asm("v_cvt_pk_bf16_f32 %0, %1, %2" : "=v"(a1) : "v"(pf0[8 * cc + 0]), "v"(pf0[8 * cc + 1]));
                asm("v_cvt_pk_bf16_f32 %0, %1, %2" : "=v"(b1) : "v"(pf0[8 * cc + 4]), "v"(pf0[8 * cc + 5]));
                asm("v_cvt_pk_bf16_f32 %0, %1, %2" : "=v"(a2) : "v"(pf0[8 * cc + 2]), "v"(pf0[8 * cc + 3]));
                asm("v_cvt_pk_bf16_f32 %0, %1, %2" : "=v"(b2) : "v"(pf0[8 * cc + 6]), "v"(pf0[8 * cc + 7]));
                asm("v_permlane32_swap_b32 %0, %1" : "+v"(a1), "+v"(b1));
                asm("v_permlane32_swap_b32 %0, %1" : "+v"(a2), "+v"(b2));
                asm("v_cvt_pk_bf16_f32 %0, %1, %2" : "=v"(a3) : "v"(pf1[8 * cc + 0]), "v"(pf1[8 * cc + 1]));
                asm("v_cvt_pk_bf16_f32 %0, %1, %2" : "=v"(b3) : "v"(pf1[8 * cc + 4]), "v"(pf1[8 * cc + 5]));
                asm("v_cvt_pk_bf16_f32 %0, %1, %2" : "=v"(a4) : "v"(pf1[8 * cc + 2]), "v"(pf1[8 * cc + 3]));
                asm("v_cvt_pk_bf16_f32 %0, %1, %2" : "=v"(b4) : "v"(pf1[8 * cc + 6]), "v"(pf1[8 * cc + 7]));
                asm("v_permlane32_swap_b32 %0, %1" : "+v"(a3), "+v"(b3));
                asm("v_permlane32_swap_b32 %0, %1" : "+v"(a4), "+v"(b4));
                u32x4 w0, w1;
                w0[0] = a1; w0[1] = a2; w0[2] = b1; w0[3] = b2;
                w1[0] = a3; w1[1] = a4; w1[2] = b3; w1[3] = b4;
                const bf16x8 bp0 = *(const bf16x8*)&w0;
                const bf16x8 bp1 = *(const bf16x8*)&w1;
                const int c = kvt * 2 + cc;
                __builtin_amdgcn_s_setprio(1);
#pragma unroll
                for (int dt = 0; dt < 2; ++dt) {
                    bf16x8 vf = *(const bf16x8*)(
                        VTs + ((dt * 32 + l31) * 8 + ((c * 2 + hh) ^ l7)) * 8);
                    o[dt][0] = __builtin_amdgcn_mfma_f32_32x32x16_bf16(vf, bp0, o[dt][0], 0, 0, 0);
                    o[dt][1] = __builtin_amdgcn_mfma_f32_32x32x16_bf16(vf, bp1, o[dt][1], 0, 0, 0);
                }
                __builtin_amdgcn_s_setprio(0);
            }
        }
        __syncthreads();   // drains prefetch vmcnt + protects buffer swap
        cur ^= 1;
    }

    // ---- epilogue per q-subtile: O^T -> O via per-wave LDS transpose ----
#pragma unroll
    for (int qs = 0; qs < 2; ++qs) {
        float lp = (lpa[qs][0] + lpa[qs][1]) + (lpa[qs][2] + lpa[qs][3]);
        lp += __shfl_xor(lp, 32);
        const int qrow = q0 + wave * 64 + qs * 32 + l31;
        if (PARTIAL) {
            if (lane < 32) lsum[((size_t)half * SEQ + qrow) * NHEADS + head] = lp;
        }
        const float inv = PARTIAL ? 1.0f : 1.0f / lp;

#pragma unroll
        for (int dt = 0; dt < 2; ++dt) {
#pragma unroll
            for (int r = 0; r < 16; ++r) {
                const int dl = (r & 3) + 8 * (r >> 2) + 4 * hh;   // 0..31
                Os[wave][l31][dl] = o[dt][qs][r] * inv;
            }
#pragma unroll
            for (int it = 0; it < 4; ++it) {
                const int qr  = it * 8 + (lane >> 3);
                const int dl2 = (lane & 7) * 4;
                const f32x4 v = *(const f32x4*)(&Os[wave][qr][dl2]);
                const int row = q0 + wave * 64 + qs * 32 + qr;
                const int col = head * DHEAD + dt * 32 + dl2;
                if (PARTIAL) {
                    *(f32x4*)(opf + ((size_t)half * SEQ + row) * DMODEL + col) = v;
                } else {
                    bf16x4 ov;
                    ov[0] = (bf16)v[0]; ov[1] = (bf16)v[1];
                    ov[2] = (bf16)v[2]; ov[3] = (bf16)v[3];
                    *(bf16x4*)(z + (size_t)row * DMODEL + col) = ov;
                }
            }
        }
    }
}

// ---------------------------------------------------------------------------
// Merge NS KV-split partials: z = (sum o_i)/(sum l_i). One block per q-row.
// ---------------------------------------------------------------------------
template<int NS>
__global__ __launch_bounds__(256)
void combine_halves(const float* __restrict__ opf, const float* __restrict__ lsum,
                    bf16* __restrict__ z) {
    const int row = blockIdx.x;
    const int c   = threadIdx.x * 4;
    const int head = c >> 6;
    float l = 0.f;
#pragma unroll
    for (int s = 0; s < NS; ++s)
        l += lsum[((size_t)s * SEQ + row) * NHEADS + head];
    float4 acc = {0.f, 0.f, 0.f, 0.f};
#pragma unroll
    for (int s = 0; s < NS; ++s) {
        const float4 ov = *(const float4*)(opf + ((size_t)s * SEQ + row) * DMODEL + c);
        acc.x += ov.x; acc.y += ov.y; acc.z += ov.z; acc.w += ov.w;
    }
    bf16x4 out;
    out[0] = (bf16)(acc.x / l);
    out[1] = (bf16)(acc.y / l);
    out[2] = (bf16)(acc.z / l);
    out[3] = (bf16)(acc.w / l);
    *(bf16x4*)(z + (size_t)row * DMODEL + c) = out;
}

// ---------------------------------------------------------------------------
extern "C" void kernel_launch(void* const* d_in, const int* in_sizes, int n_in,
                              void* d_out, int out_size, void* d_ws, size_t ws_size,
                              hipStream_t stream) {
    const float* x    = (const float*)d_in[0];
    const float* Wqkv = (const float*)d_in[1];
    const float* bqkv = (const float*)d_in[2];
    const float* Wo   = (const float*)d_in[3];
    const float* bo   = (const float*)d_in[4];
    const float* wq   = (const float*)d_in[5];
    const float* wk   = (const float*)d_in[6];
    float* out = (float*)d_out;

    bf16* qkv  = (bf16*)d_ws;                       // [4096][3072]  25.2 MB (v third unused)
    bf16* z    = qkv + (size_t)SEQ * QKV3;          // [4096][1024]   8.4 MB
    bf16* Vt   = z + (size_t)SEQ * DMODEL;          // [16][64][4096] 8.4 MB
    bf16* xb   = Vt + (size_t)NHEADS * DHEAD * SEQ; // [4096][1024]   8.4 MB
    bf16* Wqb  = xb + NX;                           // [3072][1024]   6.3 MB
    bf16* Wob  = Wqb + NW;                          // [1024][1024]   2.1 MB
    bf16* endb = Wob + NO;
    float* opf  = (float*)endb;                     // [2][4096][1024] fp32
    float* lsum2 = opf + (size_t)2 * SEQ * DMODEL;
    const size_t need2 = (size_t)((char*)(lsum2 + (size_t)2 * SEQ * NHEADS) - (char*)d_ws);

    cvt_all<<<dim3((NX + NW + NO) / 2048), 256, 0, stream>>>(x, Wqkv, Wo, xb);

    gemm_qkv<<<dim3(QKV3 / 128, SEQ / 128), 256, 0, stream>>>(
        xb, Wqb, bqkv, wq, wk, qkv, Vt);

    if (ws_size >= need2) {
        attn_fwd<2><<<dim3(NHEADS, SEQ / 256, 2), 256, 0, stream>>>(
            qkv, Vt, z, opf, lsum2);
        combine_halves<2><<<dim3(SEQ), 256, 0, stream>>>(opf, lsum2, z);
    } else {
        attn_fwd<1><<<dim3(NHEADS, SEQ / 256, 1), 256, 0, stream>>>(
            qkv, Vt, z, nullptr, nullptr);
    }

    gemm_out<<<dim3(DMODEL / 64, SEQ / 128), 256, 0, stream>>>(z, Wob, bo, out);
}